// Round 1
// baseline (5057.785 us; speedup 1.0000x reference)
//
#include <hip/hip_runtime.h>
#include <cstddef>
#include <cstdint>
#include <cmath>

#define N_TOK 32768
#define EMB   512
#define KCB   8192

#define BM 64
#define BN 64
#define DT 32
#define LDA (BM + 4)   // pad 4 floats: keeps 16B alignment, breaks bank aliasing
#define LDB (BN + 4)

// ---------------- K0: row squared norms for z and codebook ----------------
__global__ __launch_bounds__(256)
void rownorms_kernel(const float* __restrict__ z, const float* __restrict__ cb,
                     float* __restrict__ z_sq, float* __restrict__ c_sq) {
    int wave = blockIdx.x * 4 + (threadIdx.x >> 6);
    int lane = threadIdx.x & 63;
    const float* src;
    float* dst;
    if (wave < N_TOK) { src = z + (size_t)wave * EMB; dst = z_sq + wave; }
    else { int r = wave - N_TOK; src = cb + (size_t)r * EMB; dst = c_sq + r; }
    const float4* s4 = (const float4*)src;
    float s = 0.f;
#pragma unroll
    for (int h = 0; h < 2; ++h) {
        float4 v = s4[lane + (h << 6)];
        s += v.x * v.x + v.y * v.y + v.z * v.z + v.w * v.w;
    }
#pragma unroll
    for (int off = 32; off >= 1; off >>= 1) s += __shfl_xor(s, off, 64);
    if (lane == 0) *dst = s;
}

// ---------------- K1: fused distance GEMM + argmin + online softmax stats ----------------
// Block: 256 threads = 16x16, each thread owns a 4x4 microtile of the 64x64 C-tile.
// Loops over all 128 codebook tiles; stats never leave registers until the end.
__global__ __launch_bounds__(256)
void dist_kernel(const float* __restrict__ z, const float* __restrict__ cb,
                 const float* __restrict__ z_sq, const float* __restrict__ c_sq,
                 int* __restrict__ out_idx, float* __restrict__ out_ent) {
    __shared__ __align__(16) float As[DT][LDA];  // z chunk, d-major
    __shared__ __align__(16) float Bs[DT][LDB];  // codebook chunk, d-major

    const int tid = threadIdx.x;
    const int tx = tid & 15;
    const int ty = tid >> 4;
    const int brow = blockIdx.x * BM;

    float mBest[4], S0[4], S1[4];
    int iBest[4];
#pragma unroll
    for (int i = 0; i < 4; ++i) { mBest[i] = INFINITY; S0[i] = 0.f; S1[i] = 0.f; iBest[i] = 0; }

    float zs[4];
#pragma unroll
    for (int i = 0; i < 4; ++i) zs[i] = z_sq[brow + (ty << 2) + i];

    for (int kt = 0; kt < KCB / BN; ++kt) {
        float acc[4][4];
#pragma unroll
        for (int i = 0; i < 4; ++i)
#pragma unroll
            for (int j = 0; j < 4; ++j) acc[i][j] = 0.f;

        const float* ctile = cb + (size_t)kt * BN * EMB;

        for (int d0 = 0; d0 < EMB; d0 += DT) {
            __syncthreads();
#pragma unroll
            for (int h = 0; h < 2; ++h) {
                int eid = tid + (h << 8);
                int r = eid >> 3;
                int c4 = (eid & 7) << 2;
                float4 av = *(const float4*)&z[(size_t)(brow + r) * EMB + d0 + c4];
                float4 bv = *(const float4*)&ctile[(size_t)r * EMB + d0 + c4];
                As[c4 + 0][r] = av.x; As[c4 + 1][r] = av.y;
                As[c4 + 2][r] = av.z; As[c4 + 3][r] = av.w;
                Bs[c4 + 0][r] = bv.x; Bs[c4 + 1][r] = bv.y;
                Bs[c4 + 2][r] = bv.z; Bs[c4 + 3][r] = bv.w;
            }
            __syncthreads();
#pragma unroll
            for (int d = 0; d < DT; ++d) {
                float4 a = *(const float4*)&As[d][ty << 2];
                float4 b = *(const float4*)&Bs[d][tx << 2];
                float av4[4] = {a.x, a.y, a.z, a.w};
                float bv4[4] = {b.x, b.y, b.z, b.w};
#pragma unroll
                for (int i = 0; i < 4; ++i)
#pragma unroll
                    for (int j = 0; j < 4; ++j)
                        acc[i][j] = fmaf(av4[i], bv4[j], acc[i][j]);
            }
        }

        // tile epilogue: distances + online stats
        float cs[4];
#pragma unroll
        for (int j = 0; j < 4; ++j) cs[j] = c_sq[kt * BN + (tx << 2) + j];
#pragma unroll
        for (int i = 0; i < 4; ++i) {
#pragma unroll
            for (int j = 0; j < 4; ++j) {
                float d2 = zs[i] + cs[j] - 2.f * acc[i][j];
                float d = sqrtf(fmaxf(d2, 0.f));
                int code = kt * BN + (tx << 2) + j;
                if (d < mBest[i]) {
                    // new running min: rescale existing sums
                    float e = __expf(d - mBest[i]);   // first time: expf(-inf)=0
                    S0[i] = S0[i] * e + 1.f;
                    S1[i] = S1[i] * e + d;
                    mBest[i] = d;
                    iBest[i] = code;
                } else {
                    float e = __expf(mBest[i] - d);
                    S0[i] += e;
                    S1[i] += d * e;
                }
            }
        }
    }

    // merge across the 16 lanes (tx) that share each row
#pragma unroll
    for (int i = 0; i < 4; ++i) {
        float m = mBest[i], s0 = S0[i], s1 = S1[i];
        int bi = iBest[i];
#pragma unroll
        for (int off = 1; off < 16; off <<= 1) {
            float m2  = __shfl_xor(m, off, 64);
            float s02 = __shfl_xor(s0, off, 64);
            float s12 = __shfl_xor(s1, off, 64);
            int   bi2 = __shfl_xor(bi, off, 64);
            float mn = fminf(m, m2);
            float e1 = __expf(mn - m);
            float e2 = __expf(mn - m2);
            s0 = s0 * e1 + s02 * e2;
            s1 = s1 * e1 + s12 * e2;
            if (m2 < m || (m2 == m && bi2 < bi)) bi = bi2;  // first-occurrence tie rule
            m = mn;
        }
        if (tx == 0) {
            int row = brow + (ty << 2) + i;
            out_idx[row] = bi;
            // entropy = logZ + E[d];  logZ = -m + log(S0)
            out_ent[row] = -m + logf(s0) + s1 / s0;
        }
    }
}

// ---------------- K2: gather + deviation + per-row quant norm ----------------
__global__ __launch_bounds__(64)
void gather_kernel(const float* __restrict__ z, const float* __restrict__ y,
                   const float* __restrict__ et_in, const float* __restrict__ cb,
                   const int* __restrict__ idx, float* __restrict__ out_q,
                   float* __restrict__ out_et, float* __restrict__ qn_out) {
    int row = blockIdx.x;
    int lane = threadIdx.x;
    int bi = idx[row];
    const float4* q4 = (const float4*)(cb + (size_t)bi * EMB);
    const float4* z4 = (const float4*)(z + (size_t)row * EMB);
    const float4* y4 = (const float4*)(y + (size_t)row * EMB);
    float4* o4 = (float4*)(out_q + (size_t)row * EMB);
    float dev2 = 0.f, qn2 = 0.f;
#pragma unroll
    for (int h = 0; h < 2; ++h) {
        int c = lane + (h << 6);
        float4 qv = q4[c], zv = z4[c], yv = y4[c];
        o4[c] = qv;
        float dx = qv.x - yv.x, dy = qv.y - yv.y, dz = qv.z - yv.z, dw = qv.w - yv.w;
        dev2 += dx * dx + dy * dy + dz * dz + dw * dw;
        dx = zv.x - qv.x; dy = zv.y - qv.y; dz = zv.z - qv.z; dw = zv.w - qv.w;
        qn2 += dx * dx + dy * dy + dz * dz + dw * dw;
    }
#pragma unroll
    for (int off = 32; off >= 1; off >>= 1) {
        dev2 += __shfl_xor(dev2, off, 64);
        qn2 += __shfl_xor(qn2, off, 64);
    }
    if (lane == 0) {
        out_et[row] = et_in[row] + ((sqrtf(dev2) > 0.01f) ? 1.f : 0.f);
        qn_out[row] = sqrtf(qn2);
    }
}

// ---------------- K3: reduce entropy & qnorm means, broadcast quant_loss ----------------
__global__ __launch_bounds__(256)
void finalize_kernel(const float* __restrict__ ent, const float* __restrict__ qn,
                     float* __restrict__ out_loss) {
    float se = 0.f, sq = 0.f;
    for (int i = threadIdx.x; i < N_TOK; i += 256) { se += ent[i]; sq += qn[i]; }
#pragma unroll
    for (int off = 32; off >= 1; off >>= 1) {
        se += __shfl_xor(se, off, 64);
        sq += __shfl_xor(sq, off, 64);
    }
    __shared__ float we[4], wq[4];
    int w = threadIdx.x >> 6, lane = threadIdx.x & 63;
    if (lane == 0) { we[w] = se; wq[w] = sq; }
    __syncthreads();
    se = we[0] + we[1] + we[2] + we[3];
    sq = wq[0] + wq[1] + wq[2] + wq[3];
    // iter_k == 0 -> grad_error == 0 -> w == 1 for every row
    float loss = sq * (1.f / N_TOK) + 0.1f * se * (1.f / N_TOK);
    for (int i = threadIdx.x; i < N_TOK; i += 256) out_loss[i] = loss;
}

extern "C" void kernel_launch(void* const* d_in, const int* in_sizes, int n_in,
                              void* d_out, int out_size, void* d_ws, size_t ws_size,
                              hipStream_t stream) {
    const float* z  = (const float*)d_in[0];
    const float* y  = (const float*)d_in[1];
    const float* et = (const float*)d_in[2];
    const float* cb = (const float*)d_in[3];
    // iter_k (d_in[4]) is statically 0 in the reference path.

    float* out_q    = (float*)d_out;                       // [N, D]
    float* out_loss = out_q + (size_t)N_TOK * EMB;         // [N]
    float* out_et   = out_loss + N_TOK;                    // [N]

    float* wf   = (float*)d_ws;
    float* z_sq = wf;                                      // N
    float* c_sq = wf + N_TOK;                              // K
    float* ent  = wf + N_TOK + KCB;                        // N
    float* qn   = wf + 2 * N_TOK + KCB;                    // N
    int*   idx  = (int*)(wf + 3 * N_TOK + KCB);            // N

    rownorms_kernel<<<(N_TOK + KCB) / 4, 256, 0, stream>>>(z, cb, z_sq, c_sq);
    dist_kernel<<<N_TOK / BM, 256, 0, stream>>>(z, cb, z_sq, c_sq, idx, ent);
    gather_kernel<<<N_TOK, 64, 0, stream>>>(z, y, et, cb, idx, out_q, out_et, qn);
    finalize_kernel<<<1, 256, 0, stream>>>(ent, qn, out_loss);
}

// Round 2
// 1606.882 us; speedup vs baseline: 3.1476x; 3.1476x over previous
//
#include <hip/hip_runtime.h>
#include <cstddef>
#include <cstdint>
#include <cmath>

#define N_TOK 32768
#define EMB   512
#define KCB   8192
#define CH    8          // codebook col-chunks per grid dim

typedef _Float16 f16;
typedef f16 f16x8 __attribute__((ext_vector_type(8)));
typedef float f32x4 __attribute__((ext_vector_type(4)));

#define MFMA16(a, b, c) __builtin_amdgcn_mfma_f32_16x16x32_f16(a, b, c, 0, 0, 0)

__device__ inline void gload_lds16(const f16* g, f16* l) {
    __builtin_amdgcn_global_load_lds(
        (const __attribute__((address_space(1))) unsigned int*)g,
        (__attribute__((address_space(3))) unsigned int*)l, 16, 0, 0);
}

// ---------------- K0: row squared norms for z and codebook ----------------
__global__ __launch_bounds__(256)
void rownorms_kernel(const float* __restrict__ z, const float* __restrict__ cb,
                     float* __restrict__ z_sq, float* __restrict__ c_sq) {
    int wave = blockIdx.x * 4 + (threadIdx.x >> 6);
    int lane = threadIdx.x & 63;
    const float* src;
    float* dst;
    if (wave < N_TOK) { src = z + (size_t)wave * EMB; dst = z_sq + wave; }
    else { int r = wave - N_TOK; src = cb + (size_t)r * EMB; dst = c_sq + r; }
    const float4* s4 = (const float4*)src;
    float s = 0.f;
#pragma unroll
    for (int h = 0; h < 2; ++h) {
        float4 v = s4[lane + (h << 6)];
        s += v.x * v.x + v.y * v.y + v.z * v.z + v.w * v.w;
    }
#pragma unroll
    for (int off = 32; off >= 1; off >>= 1) s += __shfl_xor(s, off, 64);
    if (lane == 0) *dst = s;
}

// ---------------- K0b: split codebook to fp16 hi/lo, tiled+swizzled ----------------
// Layout: block (bt, c) = codebook tile bt (128 codes) x k-chunk c (32 dims),
// 4096 halves at blk*4096; element (r,k) at 32*r + ((8*(k>>3)) ^ (8*(r&3))) + (k&7).
__global__ __launch_bounds__(256)
void splitB_kernel(const float* __restrict__ cb, f16* __restrict__ bh,
                   f16* __restrict__ bl) {
    int blk = blockIdx.x;          // 0..1023
    int bt = blk >> 4, c = blk & 15;
    int t = threadIdx.x;
    int r = t >> 1;
    int ks = (t & 1) << 4;
    const float4* src = (const float4*)(cb + (size_t)(bt * 128 + r) * EMB + c * 32 + ks);
    float v[16];
    *(float4*)&v[0]  = src[0];
    *(float4*)&v[4]  = src[1];
    *(float4*)&v[8]  = src[2];
    *(float4*)&v[12] = src[3];
    f16x8 H[2], L[2];
#pragma unroll
    for (int j = 0; j < 16; ++j) {
        f16 h = (f16)v[j];
        f16 l = (f16)(v[j] - (float)h);
        H[j >> 3][j & 7] = h;
        L[j >> 3][j & 7] = l;
    }
    size_t base = (size_t)blk * 4096;
    int g0 = ks >> 3;
#pragma unroll
    for (int j = 0; j < 2; ++j) {
        int off = 32 * r + ((8 * (g0 + j)) ^ (8 * (r & 3)));
        *(f16x8*)(bh + base + off) = H[j];
        *(f16x8*)(bl + base + off) = L[j];
    }
}

// ---------------- K1: fp16x2 MFMA distance GEMM + fused online stats ----------------
// Grid: (N/128) x CH. Block 128 rows x 1024 cols (8 tiles of 128), 4 waves 2x2,
// each wave 64x64 (4x4 frags of 16x16x32). Stats per thread over its private col
// subset; one butterfly per block; per-(row,chunk,wave-col-half) partials to ws.
__global__ __launch_bounds__(256, 2)
void dist_kernel(const float* __restrict__ z, const f16* __restrict__ bh_t,
                 const f16* __restrict__ bl_t, const float* __restrict__ z_sq,
                 const float* __restrict__ c_sq, float4* __restrict__ partials) {
    __shared__ f16 sAh[4096], sAl[4096], sBh[4096], sBl[4096];

    const int tid = threadIdx.x;
    const int lane = tid & 63;
    const int wid = tid >> 6;
    const int bid = blockIdx.x;
    const int rt = bid >> 3, ch = bid & 7;
    const int brow = rt * 128;
    const int wrow = (wid >> 1) * 64;
    const int wcol = (wid & 1) * 64;
    const int q = lane >> 4;

    // fragment read offsets (halves) — XOR-swizzled, bank-optimal
    const int xr = 8 * (lane & 3);
    const int aoff = 32 * (wrow + (lane & 15)) + ((8 * q) ^ xr);
    const int boff = 32 * (wcol + (lane & 15)) + ((8 * q) ^ xr);

    // A reg-stage mapping: thread covers row ar, k-halves ks..ks+15 of each chunk
    const int ar = tid >> 1;
    const int aks = (tid & 1) << 4;
    const float* aptr = z + (size_t)(brow + ar) * EMB + aks;
    const int ag0 = aks >> 3;
    const int awoff0 = 32 * ar + ((8 * (ag0 + 0)) ^ (8 * (ar & 3)));
    const int awoff1 = 32 * ar + ((8 * (ag0 + 1)) ^ (8 * (ar & 3)));

    // B global_load_lds assignment: waves 0,1 -> hi; 2,3 -> lo; (wid&1) picks half
    const f16* gbase = (wid < 2) ? bh_t : bl_t;
    f16* sbase = (wid < 2) ? (f16*)sBh : (f16*)sBl;
    const int sseg = (wid & 1) * 4;

    float zs[16];
#pragma unroll
    for (int si = 0; si < 16; ++si)
        zs[si] = z_sq[brow + wrow + (si >> 2) * 16 + q * 4 + (si & 3)];

    float m_[16], s0_[16], s1_[16];
    int bi_[16];
#pragma unroll
    for (int si = 0; si < 16; ++si) {
        m_[si] = __builtin_inff(); s0_[si] = 0.f; s1_[si] = 0.f; bi_[si] = 0;
    }

    f32x4 acc[4][4];
    float4 av[4];
    {
        const float4* p = (const float4*)aptr;
        av[0] = p[0]; av[1] = p[1]; av[2] = p[2]; av[3] = p[3];
    }

    for (int it = 0; it < CH * 16 * 2 / 2; ++it) {   // 128 iters = 8 tiles x 16 chunks
        const int ct = it >> 4, c = it & 15;
        const int btile = ch * 8 + ct;
        if (c == 0) {
#pragma unroll
            for (int mi = 0; mi < 4; ++mi)
#pragma unroll
                for (int ni = 0; ni < 4; ++ni)
                    acc[mi][ni] = (f32x4){0.f, 0.f, 0.f, 0.f};
        }
        __syncthreads();   // previous chunk's LDS readers done

        // B: direct global->LDS (4 issues x 1KB per wave)
        {
            size_t gb = ((size_t)btile * 16 + c) * 4096 + (size_t)lane * 8;
#pragma unroll
            for (int i = 0; i < 4; ++i)
                gload_lds16(gbase + gb + (sseg + i) * 512, sbase + (sseg + i) * 512);
        }
        // A: convert prefetched fp32 -> h/l halves, swizzled ds_write
        {
            const float* vv = (const float*)av;
            f16x8 AH[2], AL[2];
#pragma unroll
            for (int j = 0; j < 16; ++j) {
                f16 h = (f16)vv[j];
                f16 l = (f16)(vv[j] - (float)h);
                AH[j >> 3][j & 7] = h;
                AL[j >> 3][j & 7] = l;
            }
            *(f16x8*)&sAh[awoff0] = AH[0];
            *(f16x8*)&sAh[awoff1] = AH[1];
            *(f16x8*)&sAl[awoff0] = AL[0];
            *(f16x8*)&sAl[awoff1] = AL[1];
        }
        // prefetch next chunk's A (drains at the barrier B needs anyway)
        if (it < 127) {
            const float4* p = (const float4*)(aptr + ((it + 1) & 15) * 32);
            av[0] = p[0]; av[1] = p[1]; av[2] = p[2]; av[3] = p[3];
        }
        __syncthreads();   // vmcnt+lgkm drained: LDS tiles ready

        f16x8 ah[4], al[4], bhf[4], blf[4];
#pragma unroll
        for (int x = 0; x < 4; ++x) {
            ah[x]  = *(const f16x8*)&sAh[aoff + x * 512];
            al[x]  = *(const f16x8*)&sAl[aoff + x * 512];
            bhf[x] = *(const f16x8*)&sBh[boff + x * 512];
            blf[x] = *(const f16x8*)&sBl[boff + x * 512];
        }
#pragma unroll
        for (int mi = 0; mi < 4; ++mi)
#pragma unroll
            for (int ni = 0; ni < 4; ++ni) {
                acc[mi][ni] = MFMA16(ah[mi], bhf[ni], acc[mi][ni]);
                acc[mi][ni] = MFMA16(ah[mi], blf[ni], acc[mi][ni]);
                acc[mi][ni] = MFMA16(al[mi], bhf[ni], acc[mi][ni]);
            }

        if (c == 15) {
            // tile epilogue: distances + branchless online stats
            float cs[4];
            int colb[4];
#pragma unroll
            for (int ni = 0; ni < 4; ++ni) {
                colb[ni] = btile * 128 + wcol + ni * 16 + (lane & 15);
                cs[ni] = c_sq[colb[ni]];
            }
#pragma unroll
            for (int mi = 0; mi < 4; ++mi)
#pragma unroll
                for (int reg = 0; reg < 4; ++reg) {
                    const int si = mi * 4 + reg;
                    const float zc = zs[si];
#pragma unroll
                    for (int ni = 0; ni < 4; ++ni) {
                        float a = acc[mi][ni][reg];
                        float d2 = fmaf(-2.f, a, zc + cs[ni]);
                        float d = sqrtf(fmaxf(d2, 0.f));
                        float mo = m_[si];
                        float mn = fminf(mo, d);
                        float eo = __expf(mn - mo);   // 1 if min unchanged, 0 on first
                        float en = __expf(mn - d);
                        s0_[si] = fmaf(s0_[si], eo, en);
                        s1_[si] = fmaf(s1_[si], eo, d * en);
                        bi_[si] = (d < mo) ? colb[ni] : bi_[si];
                        m_[si] = mn;
                    }
                }
        }
    }

    // butterfly merge across the 16 lanes sharing each row set
#pragma unroll
    for (int si = 0; si < 16; ++si) {
        float m = m_[si], s0 = s0_[si], s1 = s1_[si];
        int bi = bi_[si];
#pragma unroll
        for (int off = 1; off < 16; off <<= 1) {
            float mp  = __shfl_xor(m, off, 64);
            float s0p = __shfl_xor(s0, off, 64);
            float s1p = __shfl_xor(s1, off, 64);
            int   bip = __shfl_xor(bi, off, 64);
            float mn = fminf(m, mp);
            float ea = __expf(mn - m);
            float eb = __expf(mn - mp);
            s0 = s0 * ea + s0p * eb;
            s1 = s1 * ea + s1p * eb;
            bi = (mp < m || (mp == m && bip < bi)) ? bip : bi;
            m = mn;
        }
        m_[si] = m; s0_[si] = s0; s1_[si] = s1; bi_[si] = bi;
    }
    if ((lane & 15) == 0) {
        const int pidx = ch * 2 + (wid & 1);
#pragma unroll
        for (int si = 0; si < 16; ++si) {
            int row = brow + wrow + (si >> 2) * 16 + q * 4 + (si & 3);
            partials[(size_t)pidx * N_TOK + row] =
                make_float4(m_[si], s0_[si], s1_[si], __int_as_float(bi_[si]));
        }
    }
}

// ---------------- K1b: merge partial stats per row ----------------
__global__ __launch_bounds__(256)
void merge_kernel(const float4* __restrict__ partials, int* __restrict__ idx,
                  float* __restrict__ ent) {
    int row = blockIdx.x * 256 + threadIdx.x;
    float4 v = partials[row];
    float m = v.x, s0 = v.y, s1 = v.z;
    int bi = __float_as_int(v.w);
#pragma unroll
    for (int p = 1; p < 16; ++p) {
        float4 u = partials[(size_t)p * N_TOK + row];
        float mp = u.x, s0p = u.y, s1p = u.z;
        int bip = __float_as_int(u.w);
        float mn = fminf(m, mp);
        float ea = __expf(mn - m);
        float eb = __expf(mn - mp);
        s0 = s0 * ea + s0p * eb;
        s1 = s1 * ea + s1p * eb;
        bi = (mp < m || (mp == m && bip < bi)) ? bip : bi;
        m = mn;
    }
    ent[row] = -m + logf(s0) + s1 / s0;
    idx[row] = bi;
}

// ---------------- K2: gather + deviation + per-row quant norm ----------------
__global__ __launch_bounds__(64)
void gather_kernel(const float* __restrict__ z, const float* __restrict__ y,
                   const float* __restrict__ et_in, const float* __restrict__ cb,
                   const int* __restrict__ idx, float* __restrict__ out_q,
                   float* __restrict__ out_et, float* __restrict__ qn_out) {
    int row = blockIdx.x;
    int lane = threadIdx.x;
    int bi = idx[row];
    const float4* q4 = (const float4*)(cb + (size_t)bi * EMB);
    const float4* z4 = (const float4*)(z + (size_t)row * EMB);
    const float4* y4 = (const float4*)(y + (size_t)row * EMB);
    float4* o4 = (float4*)(out_q + (size_t)row * EMB);
    float dev2 = 0.f, qn2 = 0.f;
#pragma unroll
    for (int h = 0; h < 2; ++h) {
        int c = lane + (h << 6);
        float4 qv = q4[c], zv = z4[c], yv = y4[c];
        o4[c] = qv;
        float dx = qv.x - yv.x, dy = qv.y - yv.y, dz = qv.z - yv.z, dw = qv.w - yv.w;
        dev2 += dx * dx + dy * dy + dz * dz + dw * dw;
        dx = zv.x - qv.x; dy = zv.y - qv.y; dz = zv.z - qv.z; dw = zv.w - qv.w;
        qn2 += dx * dx + dy * dy + dz * dz + dw * dw;
    }
#pragma unroll
    for (int off = 32; off >= 1; off >>= 1) {
        dev2 += __shfl_xor(dev2, off, 64);
        qn2 += __shfl_xor(qn2, off, 64);
    }
    if (lane == 0) {
        out_et[row] = et_in[row] + ((sqrtf(dev2) > 0.01f) ? 1.f : 0.f);
        qn_out[row] = sqrtf(qn2);
    }
}

// ---------------- K3: reduce means, broadcast quant_loss ----------------
__global__ __launch_bounds__(256)
void finalize_kernel(const float* __restrict__ ent, const float* __restrict__ qn,
                     float* __restrict__ out_loss) {
    float se = 0.f, sq = 0.f;
    for (int i = threadIdx.x; i < N_TOK; i += 256) { se += ent[i]; sq += qn[i]; }
#pragma unroll
    for (int off = 32; off >= 1; off >>= 1) {
        se += __shfl_xor(se, off, 64);
        sq += __shfl_xor(sq, off, 64);
    }
    __shared__ float we[4], wq[4];
    int w = threadIdx.x >> 6, lane = threadIdx.x & 63;
    if (lane == 0) { we[w] = se; wq[w] = sq; }
    __syncthreads();
    se = we[0] + we[1] + we[2] + we[3];
    sq = wq[0] + wq[1] + wq[2] + wq[3];
    float loss = sq * (1.f / N_TOK) + 0.1f * se * (1.f / N_TOK);
    for (int i = threadIdx.x; i < N_TOK; i += 256) out_loss[i] = loss;
}

extern "C" void kernel_launch(void* const* d_in, const int* in_sizes, int n_in,
                              void* d_out, int out_size, void* d_ws, size_t ws_size,
                              hipStream_t stream) {
    const float* z  = (const float*)d_in[0];
    const float* y  = (const float*)d_in[1];
    const float* et = (const float*)d_in[2];
    const float* cb = (const float*)d_in[3];
    // iter_k (d_in[4]) is statically 0 in the reference path.

    float* out_q    = (float*)d_out;                       // [N, D]
    float* out_loss = out_q + (size_t)N_TOK * EMB;         // [N]
    float* out_et   = out_loss + N_TOK;                    // [N]

    f16* bh_t = (f16*)d_ws;                                // 64*16*4096 halves = 8MB
    f16* bl_t = bh_t + (size_t)64 * 16 * 4096;             // 8MB
    float4* partials = (float4*)(bl_t + (size_t)64 * 16 * 4096);  // 16*N float4 = 8MB
    float* z_sq = (float*)(partials + (size_t)16 * N_TOK);
    float* c_sq = z_sq + N_TOK;
    float* ent  = c_sq + KCB;
    float* qn   = ent + N_TOK;
    int*   idx  = (int*)(qn + N_TOK);

    rownorms_kernel<<<(N_TOK + KCB) / 4, 256, 0, stream>>>(z, cb, z_sq, c_sq);
    splitB_kernel<<<(KCB / 128) * 16, 256, 0, stream>>>(cb, bh_t, bl_t);
    dist_kernel<<<(N_TOK / 128) * CH, 256, 0, stream>>>(z, bh_t, bl_t, z_sq, c_sq, partials);
    merge_kernel<<<N_TOK / 256, 256, 0, stream>>>(partials, idx, ent);
    gather_kernel<<<N_TOK, 64, 0, stream>>>(z, y, et, cb, idx, out_q, out_et, qn);
    finalize_kernel<<<1, 256, 0, stream>>>(ent, qn, out_loss);
}

// Round 3
// 1256.611 us; speedup vs baseline: 4.0249x; 1.2787x over previous
//
#include <hip/hip_runtime.h>
#include <cstddef>
#include <cstdint>
#include <cmath>

#define N_TOK 32768
#define EMB   512
#define KCB   8192
#define CH    8          // codebook col-stripes, pinned to XCD via bid&7

typedef _Float16 f16;
typedef f16 f16x8 __attribute__((ext_vector_type(8)));
typedef float f32x4 __attribute__((ext_vector_type(4)));

#define MFMA16(a, b, c) __builtin_amdgcn_mfma_f32_16x16x32_f16(a, b, c, 0, 0, 0)

__device__ inline void gload_lds16(const f16* g, f16* l) {
    __builtin_amdgcn_global_load_lds(
        (const __attribute__((address_space(1))) unsigned int*)g,
        (__attribute__((address_space(3))) unsigned int*)l, 16, 0, 0);
}

// swizzle: halves offset of element (r, k) inside a [R][32]-half chunk image
// off = 32*r + 8*((k>>3) ^ ((r>>1)&3)) + (k&7)  -> 2-way (free) on b128 frag reads
__device__ inline int swz(int r) { return (r >> 1) & 3; }

// ---------------- K0: row squared norms for z and codebook ----------------
__global__ __launch_bounds__(256)
void rownorms_kernel(const float* __restrict__ z, const float* __restrict__ cb,
                     float* __restrict__ z_sq, float* __restrict__ c_sq) {
    int wave = blockIdx.x * 4 + (threadIdx.x >> 6);
    int lane = threadIdx.x & 63;
    const float* src;
    float* dst;
    if (wave < N_TOK) { src = z + (size_t)wave * EMB; dst = z_sq + wave; }
    else { int r = wave - N_TOK; src = cb + (size_t)r * EMB; dst = c_sq + r; }
    const float4* s4 = (const float4*)src;
    float s = 0.f;
#pragma unroll
    for (int h = 0; h < 2; ++h) {
        float4 v = s4[lane + (h << 6)];
        s += v.x * v.x + v.y * v.y + v.z * v.z + v.w * v.w;
    }
#pragma unroll
    for (int off = 32; off >= 1; off >>= 1) s += __shfl_xor(s, off, 64);
    if (lane == 0) *dst = s;
}

// ---------------- K0b: split codebook to fp16 hi/lo, tiled+swizzled ----------------
// Image: (btile of 256 codes, chunk of 32 dims) -> 8192 halves at (bt*16+c)*8192.
__global__ __launch_bounds__(256)
void splitB_kernel(const float* __restrict__ cb, f16* __restrict__ bh,
                   f16* __restrict__ bl) {
    int blk = blockIdx.x;          // 0..1023
    int bt = blk >> 5, c = (blk >> 1) & 15, hf = blk & 1;
    int t = threadIdx.x;
    int r = hf * 128 + (t >> 1);
    int ks = (t & 1) << 4;
    const float4* src = (const float4*)(cb + (size_t)(bt * 256 + r) * EMB + c * 32 + ks);
    float v[16];
    *(float4*)&v[0]  = src[0];
    *(float4*)&v[4]  = src[1];
    *(float4*)&v[8]  = src[2];
    *(float4*)&v[12] = src[3];
    f16x8 H[2], L[2];
#pragma unroll
    for (int j = 0; j < 16; ++j) {
        f16 h = (f16)v[j];
        f16 l = (f16)(v[j] - (float)h);
        H[j >> 3][j & 7] = h;
        L[j >> 3][j & 7] = l;
    }
    size_t base = ((size_t)bt * 16 + c) * 8192;
    int g0 = ks >> 3;
#pragma unroll
    for (int j = 0; j < 2; ++j) {
        int off = 32 * r + 8 * ((g0 + j) ^ swz(r));
        *(f16x8*)(bh + base + off) = H[j];
        *(f16x8*)(bl + base + off) = L[j];
    }
}

// convert 8 fp32 -> h/l f16x8 and store swizzled to LDS
__device__ inline void writeA(f16* dh, f16* dl, const float4* av, int off) {
    const float* vv = (const float*)av;
    f16x8 H, L;
#pragma unroll
    for (int j = 0; j < 8; ++j) {
        f16 h = (f16)vv[j];
        f16 l = (f16)(vv[j] - (float)h);
        H[j] = h; L[j] = l;
    }
    *(f16x8*)&dh[off] = H;
    *(f16x8*)&dl[off] = L;
}

// ---------------- K1: fp16x3 MFMA distance GEMM + fused online stats ----------------
// Grid 2048: ch = bid&7 (XCD-pinned stripe of 1024 cols), rt = bid>>3 (128 rows).
// 512 thr = 8 waves (4 row x 2 col), wave tile 32x128 (16x16x32, M_rep=2, N_rep=8).
// Double-buffered LDS (96KB dynamic), one barrier per 32-dim chunk.
__global__ __launch_bounds__(512, 2)
void dist_kernel(const float* __restrict__ z, const f16* __restrict__ bh_t,
                 const f16* __restrict__ bl_t, const float* __restrict__ z_sq,
                 const float* __restrict__ c_sq, float4* __restrict__ partials) {
    extern __shared__ __align__(16) f16 lds[];   // 2 x {Ah 4096, Al 4096, Bh 8192, Bl 8192}

    const int tid = threadIdx.x;
    const int lane = tid & 63;
    const int wid = tid >> 6;
    const int bid = blockIdx.x;
    const int ch = bid & 7;
    const int rt = bid >> 3;
    const int brow = rt * 128;

    const int la = lane & 15, q = lane >> 4;
    const int wrow = (wid >> 1) * 32;
    const int wcol = (wid & 1) * 128;

    f16* const buf0 = lds;
    f16* const buf1 = lds + 24576;

    // fragment read offsets (halves); +mi*512 / +ni*512 walks 16-row groups
    const int aoff0 = 32 * (wrow + la) + 8 * (q ^ ((la >> 1) & 3));
    const int boff0 = 32 * (wcol + la) + 8 * (q ^ ((la >> 1) & 3));

    // A staging: thread -> row ar, k-group ag (8 halves)
    const int ar = tid >> 2, ag = tid & 3;
    const int awoff = 32 * ar + 8 * (ag ^ swz(ar));
    const float* zrow = z + (size_t)(brow + ar) * EMB + ag * 8;

    // B gload role: waves 0-3 stage Bh quarters, 4-7 stage Bl quarters
    const int wq = wid & 3;
    const bool w_hi = (wid < 4);
    const int bsrc_off = wq * 2048 + lane * 8;   // per-lane global offset (halves)
    const int bdst_off = 8192 + (w_hi ? 0 : 8192) + wq * 2048;  // wave-uniform LDS

    float zs_[8];
#pragma unroll
    for (int si = 0; si < 8; ++si)
        zs_[si] = z_sq[brow + wrow + (si >> 2) * 16 + q * 4 + (si & 3)];

    float m_[8], s0_[8], s1_[8];
    int bi_[8];
#pragma unroll
    for (int si = 0; si < 8; ++si) {
        m_[si] = __builtin_inff(); s0_[si] = 0.f; s1_[si] = 0.f; bi_[si] = 0;
    }

    f32x4 acc[2][8];
    float4 avN[2];

    // ---- prologue: stage chunk 0 into buf0, prefetch chunk 1 regs ----
    {
        float4 a0[2];
        a0[0] = ((const float4*)zrow)[0];
        a0[1] = ((const float4*)zrow)[1];
        writeA(buf0, buf0 + 4096, a0, awoff);
        const f16* gb = (w_hi ? bh_t : bl_t) + ((size_t)(ch * 4) * 16 + 0) * 8192 + bsrc_off;
        f16* ld = buf0 + bdst_off;
#pragma unroll
        for (int i = 0; i < 4; ++i) gload_lds16(gb + i * 512, ld + i * 512);
        avN[0] = ((const float4*)(zrow + 32))[0];
        avN[1] = ((const float4*)(zrow + 32))[1];
        __syncthreads();
    }

    for (int s = 0; s < 64; ++s) {
        const int cur = s & 1;
        const int c = s & 15, bt = s >> 4;
        f16* const bufc = cur ? buf1 : buf0;
        f16* const bufn = cur ? buf0 : buf1;

        if (c == 0) {
#pragma unroll
            for (int mi = 0; mi < 2; ++mi)
#pragma unroll
                for (int ni = 0; ni < 8; ++ni)
                    acc[mi][ni] = (f32x4){0.f, 0.f, 0.f, 0.f};
        }

        // ---- stage next chunk into bufn ----
        if (s < 63) {
            const int s1 = s + 1;
            const int btile1 = ch * 4 + (s1 >> 4);
            const f16* gb = (w_hi ? bh_t : bl_t) +
                            ((size_t)btile1 * 16 + (s1 & 15)) * 8192 + bsrc_off;
            f16* ld = bufn + bdst_off;
#pragma unroll
            for (int i = 0; i < 4; ++i) gload_lds16(gb + i * 512, ld + i * 512);
            writeA(bufn, bufn + 4096, avN, awoff);
            if (s < 62) {
                const float* p = zrow + ((s + 2) & 15) * 32;
                avN[0] = ((const float4*)p)[0];
                avN[1] = ((const float4*)p)[1];
            }
        }

        // ---- compute current chunk ----
        f16* const Ah = bufc;
        f16* const Al = bufc + 4096;
        f16* const Bh = bufc + 8192;
        f16* const Bl = bufc + 16384;
        f16x8 ah[2], al[2];
#pragma unroll
        for (int mi = 0; mi < 2; ++mi) {
            ah[mi] = *(const f16x8*)&Ah[aoff0 + mi * 512];
            al[mi] = *(const f16x8*)&Al[aoff0 + mi * 512];
        }
#pragma unroll
        for (int nh = 0; nh < 2; ++nh) {
            f16x8 bh4[4], bl4[4];
#pragma unroll
            for (int j = 0; j < 4; ++j) {
                bh4[j] = *(const f16x8*)&Bh[boff0 + (nh * 4 + j) * 512];
                bl4[j] = *(const f16x8*)&Bl[boff0 + (nh * 4 + j) * 512];
            }
            __builtin_amdgcn_s_setprio(1);
#pragma unroll
            for (int mi = 0; mi < 2; ++mi)
#pragma unroll
                for (int j = 0; j < 4; ++j) {
                    const int ni = nh * 4 + j;
                    acc[mi][ni] = MFMA16(ah[mi], bh4[j], acc[mi][ni]);
                    acc[mi][ni] = MFMA16(ah[mi], bl4[j], acc[mi][ni]);
                    acc[mi][ni] = MFMA16(al[mi], bh4[j], acc[mi][ni]);
                }
            __builtin_amdgcn_s_setprio(0);
        }

        // ---- btile epilogue: distances + branchless online stats ----
        if (c == 15) {
            const int btile = ch * 4 + bt;
            float cs[8];
            int colb[8];
#pragma unroll
            for (int ni = 0; ni < 8; ++ni) {
                colb[ni] = btile * 256 + wcol + ni * 16 + la;
                cs[ni] = c_sq[colb[ni]];
            }
#pragma unroll
            for (int mi = 0; mi < 2; ++mi)
#pragma unroll
                for (int reg = 0; reg < 4; ++reg) {
                    const int si = mi * 4 + reg;
                    const float zc = zs_[si];
#pragma unroll
                    for (int ni = 0; ni < 8; ++ni) {
                        float a = acc[mi][ni][reg];
                        float d2 = fmaf(-2.f, a, zc + cs[ni]);
                        float d = sqrtf(fmaxf(d2, 0.f));
                        float mo = m_[si];
                        float mn = fminf(mo, d);
                        float eo = __expf(mn - mo);
                        float en = __expf(mn - d);
                        s0_[si] = fmaf(s0_[si], eo, en);
                        s1_[si] = fmaf(s1_[si], eo, d * en);
                        bi_[si] = (d < mo) ? colb[ni] : bi_[si];
                        m_[si] = mn;
                    }
                }
        }
        __syncthreads();
    }

    // butterfly merge across the 16 lanes sharing each row
#pragma unroll
    for (int si = 0; si < 8; ++si) {
        float m = m_[si], s0 = s0_[si], s1 = s1_[si];
        int bi = bi_[si];
#pragma unroll
        for (int off = 1; off < 16; off <<= 1) {
            float mp  = __shfl_xor(m, off, 64);
            float s0p = __shfl_xor(s0, off, 64);
            float s1p = __shfl_xor(s1, off, 64);
            int   bip = __shfl_xor(bi, off, 64);
            float mn = fminf(m, mp);
            float ea = __expf(mn - m);
            float eb = __expf(mn - mp);
            s0 = s0 * ea + s0p * eb;
            s1 = s1 * ea + s1p * eb;
            bi = (mp < m || (mp == m && bip < bi)) ? bip : bi;
            m = mn;
        }
        m_[si] = m; s0_[si] = s0; s1_[si] = s1; bi_[si] = bi;
    }
    if (la == 0) {
        const int pidx = ch * 2 + (wid & 1);
#pragma unroll
        for (int si = 0; si < 8; ++si) {
            int row = brow + wrow + (si >> 2) * 16 + q * 4 + (si & 3);
            partials[(size_t)pidx * N_TOK + row] =
                make_float4(m_[si], s0_[si], s1_[si], __int_as_float(bi_[si]));
        }
    }
}

// ---------------- K1b: merge partial stats per row ----------------
__global__ __launch_bounds__(256)
void merge_kernel(const float4* __restrict__ partials, int* __restrict__ idx,
                  float* __restrict__ ent) {
    int row = blockIdx.x * 256 + threadIdx.x;
    float4 v = partials[row];
    float m = v.x, s0 = v.y, s1 = v.z;
    int bi = __float_as_int(v.w);
#pragma unroll
    for (int p = 1; p < 16; ++p) {
        float4 u = partials[(size_t)p * N_TOK + row];
        float mp = u.x, s0p = u.y, s1p = u.z;
        int bip = __float_as_int(u.w);
        float mn = fminf(m, mp);
        float ea = __expf(mn - m);
        float eb = __expf(mn - mp);
        s0 = s0 * ea + s0p * eb;
        s1 = s1 * ea + s1p * eb;
        bi = (mp < m || (mp == m && bip < bi)) ? bip : bi;
        m = mn;
    }
    ent[row] = -m + logf(s0) + s1 / s0;
    idx[row] = bi;
}

// ---------------- K2: gather + deviation + per-row quant norm ----------------
__global__ __launch_bounds__(256)
void gather_kernel(const float* __restrict__ z, const float* __restrict__ y,
                   const float* __restrict__ et_in, const float* __restrict__ cb,
                   const int* __restrict__ idx, float* __restrict__ out_q,
                   float* __restrict__ out_et, float* __restrict__ qn_out) {
    int row = blockIdx.x * 4 + (threadIdx.x >> 6);
    int lane = threadIdx.x & 63;
    int bi = idx[row];
    const float4* q4 = (const float4*)(cb + (size_t)bi * EMB);
    const float4* z4 = (const float4*)(z + (size_t)row * EMB);
    const float4* y4 = (const float4*)(y + (size_t)row * EMB);
    float4* o4 = (float4*)(out_q + (size_t)row * EMB);
    float dev2 = 0.f, qn2 = 0.f;
#pragma unroll
    for (int h = 0; h < 2; ++h) {
        int c = lane + (h << 6);
        float4 qv = q4[c], zv = z4[c], yv = y4[c];
        o4[c] = qv;
        float dx = qv.x - yv.x, dy = qv.y - yv.y, dz = qv.z - yv.z, dw = qv.w - yv.w;
        dev2 += dx * dx + dy * dy + dz * dz + dw * dw;
        dx = zv.x - qv.x; dy = zv.y - qv.y; dz = zv.z - qv.z; dw = zv.w - qv.w;
        qn2 += dx * dx + dy * dy + dz * dz + dw * dw;
    }
#pragma unroll
    for (int off = 32; off >= 1; off >>= 1) {
        dev2 += __shfl_xor(dev2, off, 64);
        qn2 += __shfl_xor(qn2, off, 64);
    }
    if (lane == 0) {
        out_et[row] = et_in[row] + ((sqrtf(dev2) > 0.01f) ? 1.f : 0.f);
        qn_out[row] = sqrtf(qn2);
    }
}

// ---------------- K3: reduce means, broadcast quant_loss ----------------
__global__ __launch_bounds__(1024)
void finalize_kernel(const float* __restrict__ ent, const float* __restrict__ qn,
                     float* __restrict__ out_loss) {
    float se = 0.f, sq = 0.f;
    for (int i = threadIdx.x; i < N_TOK; i += 1024) { se += ent[i]; sq += qn[i]; }
#pragma unroll
    for (int off = 32; off >= 1; off >>= 1) {
        se += __shfl_xor(se, off, 64);
        sq += __shfl_xor(sq, off, 64);
    }
    __shared__ float we[16], wq[16];
    int w = threadIdx.x >> 6, lane = threadIdx.x & 63;
    if (lane == 0) { we[w] = se; wq[w] = sq; }
    __syncthreads();
    se = 0.f; sq = 0.f;
#pragma unroll
    for (int i = 0; i < 16; ++i) { se += we[i]; sq += wq[i]; }
    float loss = sq * (1.f / N_TOK) + 0.1f * se * (1.f / N_TOK);
    for (int i = threadIdx.x; i < N_TOK; i += 1024) out_loss[i] = loss;
}

extern "C" void kernel_launch(void* const* d_in, const int* in_sizes, int n_in,
                              void* d_out, int out_size, void* d_ws, size_t ws_size,
                              hipStream_t stream) {
    const float* z  = (const float*)d_in[0];
    const float* y  = (const float*)d_in[1];
    const float* et = (const float*)d_in[2];
    const float* cb = (const float*)d_in[3];
    // iter_k (d_in[4]) is statically 0 in the reference path.

    float* out_q    = (float*)d_out;                       // [N, D]
    float* out_loss = out_q + (size_t)N_TOK * EMB;         // [N]
    float* out_et   = out_loss + N_TOK;                    // [N]

    f16* bh_t = (f16*)d_ws;                                // 8MB
    f16* bl_t = bh_t + (size_t)KCB * EMB;                  // 8MB
    float4* partials = (float4*)(bl_t + (size_t)KCB * EMB); // 16*N float4 = 8MB
    float* z_sq = (float*)(partials + (size_t)16 * N_TOK);
    float* c_sq = z_sq + N_TOK;
    float* ent  = c_sq + KCB;
    float* qn   = ent + N_TOK;
    int*   idx  = (int*)(qn + N_TOK);

    hipFuncSetAttribute((const void*)dist_kernel,
                        hipFuncAttributeMaxDynamicSharedMemorySize, 98304);

    rownorms_kernel<<<(N_TOK + KCB) / 4, 256, 0, stream>>>(z, cb, z_sq, c_sq);
    splitB_kernel<<<1024, 256, 0, stream>>>(cb, bh_t, bl_t);
    dist_kernel<<<2048, 512, 98304, stream>>>(z, bh_t, bl_t, z_sq, c_sq, partials);
    merge_kernel<<<N_TOK / 256, 256, 0, stream>>>(partials, idx, ent);
    gather_kernel<<<N_TOK / 4, 256, 0, stream>>>(z, y, et, cb, idx, out_q, out_et, qn);
    finalize_kernel<<<1, 1024, 0, stream>>>(ent, qn, out_loss);
}